// Round 6
// baseline (322.759 us; speedup 1.0000x reference)
//
#include <hip/hip_runtime.h>
#include <hip/hip_bf16.h>

#define N_NODES 100000
#define N_EDGES 1600000
#define IN_F 128
#define OUT_F 64

#define ZERO_BLOCKS 99          // blocks 0..97 zero deg; block 98 computes wa1/wa2
#define CNT_BLOCKS 391          // x4096 edges = 1,601,536 >= N_EDGES
#define SCAN_BLOCKS 98          // 98*1024 = 100,352 >= N_NODES
#define GEMM_BLOCKS 1250

typedef __attribute__((ext_vector_type(8))) short short8;
typedef __attribute__((ext_vector_type(4))) float f32x4;

#define LDS_PITCH 136

__device__ __forceinline__ unsigned short f2bf(float x) {
    unsigned u = __float_as_uint(x);
    return (unsigned short)((u + 0x7FFFu + ((u >> 16) & 1u)) >> 16);  // RNE
}
__device__ __forceinline__ float bf2f_u(unsigned short b) {
    return __uint_as_float((unsigned)b << 16);
}

// ---------------------------------------------------------------------------
// K0: zero deg[] (blocks 0..97); block 98 computes wa1 = W@a1, wa2 = W@a2.
// ---------------------------------------------------------------------------
__global__ __launch_bounds__(1024) void k_zero(
    int* __restrict__ deg, const float* __restrict__ W,
    const float* __restrict__ a1, const float* __restrict__ a2,
    float* __restrict__ wa1, float* __restrict__ wa2)
{
    const int bid = blockIdx.x;
    if (bid == SCAN_BLOCKS) {            // wa block
        const int k = threadIdx.x;
        if (k < IN_F) {
            float s1 = 0.f, s2 = 0.f;
            #pragma unroll 8
            for (int f = 0; f < OUT_F; f++) {
                const float w = W[k * OUT_F + f];
                s1 += w * a1[f];
                s2 += w * a2[f];
            }
            wa1[k] = s1;
            wa2[k] = s2;
        }
        return;
    }
    const int i = bid * 1024 + threadIdx.x;
    if (i < N_NODES) deg[i] = 0;
}

// ---------------------------------------------------------------------------
// K1: per-node degree histogram via global atomics (uniform, low contention).
// ---------------------------------------------------------------------------
__global__ __launch_bounds__(1024) void k_count(
    const int* __restrict__ ei, int* __restrict__ deg)
{
    const int base = blockIdx.x * 4096 + threadIdx.x;
    #pragma unroll
    for (int k = 0; k < 4; k++) {
        const int e = base + k * 1024;
        if (e < N_EDGES) atomicAdd(&deg[ei[e]], 1);
    }
}

// ---------------------------------------------------------------------------
// K2a: per-1024-chunk totals of deg
// ---------------------------------------------------------------------------
__global__ __launch_bounds__(256) void k_scanA(const int* __restrict__ deg,
                                               int* __restrict__ bsum)
{
    __shared__ int sd[256];
    const int t = threadIdx.x;
    const int i0 = blockIdx.x * 1024 + t * 4;
    int s = 0;
    #pragma unroll
    for (int k = 0; k < 4; k++) {
        const int i = i0 + k;
        s += (i < N_NODES) ? deg[i] : 0;
    }
    sd[t] = s; __syncthreads();
    for (int off = 128; off >= 1; off >>= 1) {
        if (t < off) sd[t] += sd[t + off];
        __syncthreads();
    }
    if (t == 0) bsum[blockIdx.x] = sd[0];
}

// ---------------------------------------------------------------------------
// K2b: exclusive scan of deg -> rowptr and cur (place cursors)
// ---------------------------------------------------------------------------
__global__ __launch_bounds__(256) void k_scanC(const int* __restrict__ deg,
                                               const int* __restrict__ bsum,
                                               int* __restrict__ rowptr,
                                               int* __restrict__ cur)
{
    __shared__ int red[256];
    __shared__ int ts[256];
    const int t = threadIdx.x;

    int pv = 0;
    for (int i = t; i < (int)blockIdx.x; i += 256) pv += bsum[i];
    red[t] = pv; __syncthreads();
    for (int off = 128; off >= 1; off >>= 1) {
        if (t < off) red[t] += red[t + off];
        __syncthreads();
    }
    const int bpref = red[0];

    const int i0 = blockIdx.x * 1024 + t * 4;
    int v[4]; int s = 0;
    #pragma unroll
    for (int k = 0; k < 4; k++) {
        const int i = i0 + k;
        v[k] = (i < N_NODES) ? deg[i] : 0;
        s += v[k];
    }
    ts[t] = s; __syncthreads();
    for (int off = 1; off < 256; off <<= 1) {
        const int x = (t >= off) ? ts[t - off] : 0;
        __syncthreads();
        ts[t] += x;
        __syncthreads();
    }
    int excl = ts[t] - s + bpref;
    #pragma unroll
    for (int k = 0; k < 4; k++) {
        const int i = i0 + k;
        if (i < N_NODES) { rowptr[i] = excl; cur[i] = excl; }
        excl += v[k];
    }
    if (blockIdx.x == 0 && t == 0) rowptr[N_NODES] = N_EDGES;
}

// ---------------------------------------------------------------------------
// K3: Wh = h @ W via bf16 MFMA; f1/f2 fused in fp32. Wh stored bf16.
// (round-2 proven version, verbatim)
// ---------------------------------------------------------------------------
__global__ __launch_bounds__(256) void k_gemm(
    const float* __restrict__ h, const float* __restrict__ W,
    const float* __restrict__ wa1, const float* __restrict__ wa2,
    unsigned short* __restrict__ Whb, float* __restrict__ f1, float* __restrict__ f2)
{
    __shared__ unsigned short Wt[OUT_F * LDS_PITCH];
    __shared__ unsigned short Al[16 * LDS_PITCH];

    const int tid  = threadIdx.x;
    const int lane = tid & 63;
    const int wav  = tid >> 6;
    const int quad = lane >> 4;
    const int nl   = lane & 15;

    for (int i = tid; i < IN_F * OUT_F; i += 256) {
        const int k = i >> 6, f = i & 63;
        Wt[f * LDS_PITCH + k] = f2bf(W[i]);
    }
    __syncthreads();

    short8 bfrag[4];
    #pragma unroll
    for (int ch = 0; ch < 4; ch++)
        bfrag[ch] = *(const short8*)&Wt[(wav * 16 + nl) * LDS_PITCH + ch * 32 + quad * 8];

    const int srow = tid >> 4;
    const int sc   = tid & 15;
    float w1r[8], w2r[8];
    #pragma unroll
    for (int j = 0; j < 8; j++) { w1r[j] = wa1[sc * 8 + j]; w2r[j] = wa2[sc * 8 + j]; }

    const int ntiles = N_NODES / 16;
    for (int tile = blockIdx.x; tile < ntiles; tile += gridDim.x) {
        const int base = tile * 16;
        __syncthreads();

        const float4 v0 = *(const float4*)&h[(base + srow) * IN_F + sc * 8];
        const float4 v1 = *(const float4*)&h[(base + srow) * IN_F + sc * 8 + 4];
        float p1 = v0.x * w1r[0] + v0.y * w1r[1] + v0.z * w1r[2] + v0.w * w1r[3]
                 + v1.x * w1r[4] + v1.y * w1r[5] + v1.z * w1r[6] + v1.w * w1r[7];
        float p2 = v0.x * w2r[0] + v0.y * w2r[1] + v0.z * w2r[2] + v0.w * w2r[3]
                 + v1.x * w2r[4] + v1.y * w2r[5] + v1.z * w2r[6] + v1.w * w2r[7];
        #pragma unroll
        for (int m = 8; m >= 1; m >>= 1) {
            p1 += __shfl_xor(p1, m, 64);
            p2 += __shfl_xor(p2, m, 64);
        }
        if (sc == 0) { f1[base + srow] = p1; f2[base + srow] = p2; }

        uint4 packed;
        packed.x = (unsigned)f2bf(v0.x) | ((unsigned)f2bf(v0.y) << 16);
        packed.y = (unsigned)f2bf(v0.z) | ((unsigned)f2bf(v0.w) << 16);
        packed.z = (unsigned)f2bf(v1.x) | ((unsigned)f2bf(v1.y) << 16);
        packed.w = (unsigned)f2bf(v1.z) | ((unsigned)f2bf(v1.w) << 16);
        *(uint4*)&Al[srow * LDS_PITCH + sc * 8] = packed;

        __syncthreads();

        f32x4 acc = {0.f, 0.f, 0.f, 0.f};
        #pragma unroll
        for (int ch = 0; ch < 4; ch++) {
            const short8 afrag = *(const short8*)&Al[nl * LDS_PITCH + ch * 32 + quad * 8];
            acc = __builtin_amdgcn_mfma_f32_16x16x32_bf16(afrag, bfrag[ch], acc, 0, 0, 0);
        }

        const int col = wav * 16 + nl;
        #pragma unroll
        for (int r = 0; r < 4; r++)
            Whb[(base + quad * 4 + r) * OUT_F + col] = f2bf(acc[r]);
    }
}

// ---------------------------------------------------------------------------
// K4: direct CSR placement — each edge goes straight to its row-grouped
// final slot via a returning global atomic on cur[row]. Replaces the
// bucket scatter + full sort pass. pair = {col, eexp}.
// ---------------------------------------------------------------------------
__global__ __launch_bounds__(1024) void k_place(
    const int* __restrict__ ei,
    const float* __restrict__ f1,
    const float* __restrict__ f2,
    int* __restrict__ cur,
    uint2* __restrict__ pairs2)
{
    const int base = blockIdx.x * 4096 + threadIdx.x;

    int r[4], cl[4];
    bool ok[4];
    #pragma unroll
    for (int k = 0; k < 4; k++) {
        const int e = base + k * 1024;
        ok[k] = (e < N_EDGES);
        r[k]  = ok[k] ? ei[e] : 0;
        cl[k] = ok[k] ? ei[N_EDGES + e] : 0;
    }
    float ee[4];
    #pragma unroll
    for (int k = 0; k < 4; k++) {
        float x = f1[r[k]] + f2[cl[k]];
        x = (x >= 0.f) ? x : 0.2f * x;
        ee[k] = __expf(x);
    }
    #pragma unroll
    for (int k = 0; k < 4; k++) {
        if (ok[k]) {
            const int pos = atomicAdd(&cur[r[k]], 1);
            pairs2[pos] = make_uint2((unsigned)cl[k], __float_as_uint(ee[k]));
        }
    }
}

// ---------------------------------------------------------------------------
// K5: wave-per-node aggregation — proven 57.6us structure, verbatim.
// ---------------------------------------------------------------------------
__global__ __launch_bounds__(256) void k_agg(
    const int* __restrict__ rowptr,
    const uint2* __restrict__ pairs2,
    const unsigned short* __restrict__ Whb,
    float* __restrict__ out)
{
    const int wid  = (blockIdx.x * 256 + threadIdx.x) >> 6;
    const int lane = threadIdx.x & 63;
    if (wid >= N_NODES) return;

    const int start = rowptr[wid];
    const int end   = rowptr[wid + 1];

    float acc = 0.f, s = 0.f;
    int j = start;

    for (; j + 8 <= end; j += 8) {
        uint2 p[8];
        #pragma unroll
        for (int k = 0; k < 8; k++) p[k] = pairs2[j + k];
        float wh[8];
        #pragma unroll
        for (int k = 0; k < 8; k++)
            wh[k] = bf2f_u(Whb[(((int)(p[k].x & 0x1FFFFu)) << 6) + lane]);
        #pragma unroll
        for (int k = 0; k < 8; k++) {
            const float ee = __uint_as_float(p[k].y);
            acc += ee * wh[k];
            s   += ee;
        }
    }
    for (; j + 4 <= end; j += 4) {
        uint2 p[4];
        #pragma unroll
        for (int k = 0; k < 4; k++) p[k] = pairs2[j + k];
        float wh[4];
        #pragma unroll
        for (int k = 0; k < 4; k++)
            wh[k] = bf2f_u(Whb[(((int)(p[k].x & 0x1FFFFu)) << 6) + lane]);
        #pragma unroll
        for (int k = 0; k < 4; k++) {
            const float ee = __uint_as_float(p[k].y);
            acc += ee * wh[k];
            s   += ee;
        }
    }
    for (; j < end; j++) {
        const uint2 p = pairs2[j];
        const float ee = __uint_as_float(p.y);
        acc += ee * bf2f_u(Whb[(((int)(p.x & 0x1FFFFu)) << 6) + lane]);
        s   += ee;
    }

    const float r = acc / (s + 1e-10f);
    out[wid * OUT_F + lane] = (r > 0.f) ? r : expm1f(r);
}

extern "C" void kernel_launch(void* const* d_in, const int* in_sizes, int n_in,
                              void* d_out, int out_size, void* d_ws, size_t ws_size,
                              hipStream_t stream) {
    const float* h  = (const float*)d_in[0];
    const float* W  = (const float*)d_in[1];
    const float* a1 = (const float*)d_in[2];
    const float* a2 = (const float*)d_in[3];
    const int* ei   = (const int*)d_in[4];
    float* out      = (float*)d_out;

    float* ws = (float*)d_ws;
    unsigned short* Whb = (unsigned short*)ws;        // 6.4M ushort = 3.2M floats
    float* f1     = ws + 3200000;                     // 100,000
    float* f2     = f1 + N_NODES;                     // 100,000
    float* wa1    = f2 + N_NODES;                     // 128
    float* wa2    = wa1 + 128;                        // 128
    int*   deg    = (int*)(wa2 + 128);                // 100,000
    int*   bsum   = deg + N_NODES;                    // 98 (pad 128)
    int*   rowptr = bsum + 128;                       // 100,001
    int*   cur    = rowptr + 100001;                  // 100,000
    int*   pad    = cur + N_NODES;
    if ((size_t)(pad - (int*)ws) & 1) pad++;          // 8B align
    uint2* pairs2 = (uint2*)pad;                      // 1.6M x 8B

    k_zero  <<<ZERO_BLOCKS, 1024, 0, stream>>>(deg, W, a1, a2, wa1, wa2);
    k_count <<<CNT_BLOCKS, 1024, 0, stream>>>(ei, deg);
    k_scanA <<<SCAN_BLOCKS, 256, 0, stream>>>(deg, bsum);
    k_scanC <<<SCAN_BLOCKS, 256, 0, stream>>>(deg, bsum, rowptr, cur);
    k_gemm  <<<GEMM_BLOCKS, 256, 0, stream>>>(h, W, wa1, wa2, Whb, f1, f2);
    k_place <<<CNT_BLOCKS, 1024, 0, stream>>>(ei, f1, f2, cur, pairs2);
    k_agg   <<<(N_NODES * 64 + 255) / 256, 256, 0, stream>>>(rowptr, pairs2, Whb, out);
}

// Round 7
// 229.212 us; speedup vs baseline: 1.4081x; 1.4081x over previous
//
#include <hip/hip_runtime.h>
#include <hip/hip_bf16.h>

#define N_NODES 100000
#define N_EDGES 1600000
#define IN_F 128
#define OUT_F 64

#define RPB 64                        // rows per bucket
#define NB  1563                      // ceil(100000/64)
#define C_CHUNKS 250                  // edge chunks (scatter/hist blocks)
#define CHUNK 6400                    // edges per chunk; 250*6400 = 1,600,000
#define M_CNT (NB * C_CHUNKS)         // 390,750 bucket-major counters
#define SCANA_BLOCKS ((M_CNT + 1023) / 1024)   // 382
#define SORT_LDS_CAP 2048             // bucket len ~Poisson(1024); cap w/ fallback

typedef __attribute__((ext_vector_type(8))) short short8;
typedef __attribute__((ext_vector_type(4))) float f32x4;

#define LDS_PITCH 136

__device__ __forceinline__ unsigned short f2bf(float x) {
    unsigned u = __float_as_uint(x);
    return (unsigned short)((u + 0x7FFFu + ((u >> 16) & 1u)) >> 16);  // RNE
}
__device__ __forceinline__ float bf2f_u(unsigned short b) {
    return __uint_as_float((unsigned)b << 16);
}

// ---------------------------------------------------------------------------
// K1: per-chunk bucket histogram -> cnt[b*C_CHUNKS + c]; block C_CHUNKS
// additionally computes wa1 = W@a1, wa2 = W@a2 (fused, saves a launch).
// ---------------------------------------------------------------------------
__global__ __launch_bounds__(1024) void k_hist(
    const int* __restrict__ ei, int* __restrict__ cnt,
    const float* __restrict__ W, const float* __restrict__ a1,
    const float* __restrict__ a2, float* __restrict__ wa1, float* __restrict__ wa2)
{
    __shared__ int hl[NB];
    const int c = blockIdx.x;
    if (c == C_CHUNKS) {                 // fused k_wa
        const int k = threadIdx.x;
        if (k < IN_F) {
            float s1 = 0.f, s2 = 0.f;
            #pragma unroll 8
            for (int f = 0; f < OUT_F; f++) {
                const float w = W[k * OUT_F + f];
                s1 += w * a1[f];
                s2 += w * a2[f];
            }
            wa1[k] = s1;
            wa2[k] = s2;
        }
        return;
    }
    for (int i = threadIdx.x; i < NB; i += 1024) hl[i] = 0;
    __syncthreads();
    const int e0 = c * CHUNK;
    for (int i = threadIdx.x; i < CHUNK; i += 1024)
        atomicAdd(&hl[ei[e0 + i] >> 6], 1);
    __syncthreads();
    for (int b = threadIdx.x; b < NB; b += 1024)
        cnt[b * C_CHUNKS + c] = hl[b];
}

// ---------------------------------------------------------------------------
// K2: Wh = h @ W via bf16 MFMA; f1/f2 fused in fp32. Wh stored bf16.
// ---------------------------------------------------------------------------
__global__ __launch_bounds__(256) void k_gemm(
    const float* __restrict__ h, const float* __restrict__ W,
    const float* __restrict__ wa1, const float* __restrict__ wa2,
    unsigned short* __restrict__ Whb, float* __restrict__ f1, float* __restrict__ f2)
{
    __shared__ unsigned short Wt[OUT_F * LDS_PITCH];
    __shared__ unsigned short Al[16 * LDS_PITCH];

    const int tid  = threadIdx.x;
    const int lane = tid & 63;
    const int wav  = tid >> 6;
    const int quad = lane >> 4;
    const int nl   = lane & 15;

    for (int i = tid; i < IN_F * OUT_F; i += 256) {
        const int k = i >> 6, f = i & 63;
        Wt[f * LDS_PITCH + k] = f2bf(W[i]);
    }
    __syncthreads();

    short8 bfrag[4];
    #pragma unroll
    for (int ch = 0; ch < 4; ch++)
        bfrag[ch] = *(const short8*)&Wt[(wav * 16 + nl) * LDS_PITCH + ch * 32 + quad * 8];

    const int srow = tid >> 4;
    const int sc   = tid & 15;
    float w1r[8], w2r[8];
    #pragma unroll
    for (int j = 0; j < 8; j++) { w1r[j] = wa1[sc * 8 + j]; w2r[j] = wa2[sc * 8 + j]; }

    const int ntiles = N_NODES / 16;
    for (int tile = blockIdx.x; tile < ntiles; tile += gridDim.x) {
        const int base = tile * 16;
        __syncthreads();

        const float4 v0 = *(const float4*)&h[(base + srow) * IN_F + sc * 8];
        const float4 v1 = *(const float4*)&h[(base + srow) * IN_F + sc * 8 + 4];
        float p1 = v0.x * w1r[0] + v0.y * w1r[1] + v0.z * w1r[2] + v0.w * w1r[3]
                 + v1.x * w1r[4] + v1.y * w1r[5] + v1.z * w1r[6] + v1.w * w1r[7];
        float p2 = v0.x * w2r[0] + v0.y * w2r[1] + v0.z * w2r[2] + v0.w * w2r[3]
                 + v1.x * w2r[4] + v1.y * w2r[5] + v1.z * w2r[6] + v1.w * w2r[7];
        #pragma unroll
        for (int m = 8; m >= 1; m >>= 1) {
            p1 += __shfl_xor(p1, m, 64);
            p2 += __shfl_xor(p2, m, 64);
        }
        if (sc == 0) { f1[base + srow] = p1; f2[base + srow] = p2; }

        uint4 packed;
        packed.x = (unsigned)f2bf(v0.x) | ((unsigned)f2bf(v0.y) << 16);
        packed.y = (unsigned)f2bf(v0.z) | ((unsigned)f2bf(v0.w) << 16);
        packed.z = (unsigned)f2bf(v1.x) | ((unsigned)f2bf(v1.y) << 16);
        packed.w = (unsigned)f2bf(v1.z) | ((unsigned)f2bf(v1.w) << 16);
        *(uint4*)&Al[srow * LDS_PITCH + sc * 8] = packed;

        __syncthreads();

        f32x4 acc = {0.f, 0.f, 0.f, 0.f};
        #pragma unroll
        for (int ch = 0; ch < 4; ch++) {
            const short8 afrag = *(const short8*)&Al[nl * LDS_PITCH + ch * 32 + quad * 8];
            acc = __builtin_amdgcn_mfma_f32_16x16x32_bf16(afrag, bfrag[ch], acc, 0, 0, 0);
        }

        const int col = wav * 16 + nl;
        #pragma unroll
        for (int r = 0; r < 4; r++)
            Whb[(base + quad * 4 + r) * OUT_F + col] = f2bf(acc[r]);
    }
}

// ---------------------------------------------------------------------------
// K3a: per-1024-chunk totals of cnt
// ---------------------------------------------------------------------------
__global__ __launch_bounds__(256) void k_scanA(const int* __restrict__ cnt,
                                               int* __restrict__ bsum)
{
    __shared__ int sd[256];
    const int t = threadIdx.x;
    const int i0 = blockIdx.x * 1024 + t * 4;
    int s = 0;
    #pragma unroll
    for (int k = 0; k < 4; k++) {
        const int i = i0 + k;
        s += (i < M_CNT) ? cnt[i] : 0;
    }
    sd[t] = s; __syncthreads();
    for (int off = 128; off >= 1; off >>= 1) {
        if (t < off) sd[t] += sd[t + off];
        __syncthreads();
    }
    if (t == 0) bsum[blockIdx.x] = sd[0];
}

// ---------------------------------------------------------------------------
// K3b: in-place exclusive scan of cnt (each block reduces its bsum prefix)
// ---------------------------------------------------------------------------
__global__ __launch_bounds__(256) void k_scanC(int* __restrict__ cnt,
                                               const int* __restrict__ bsum)
{
    __shared__ int red[256];
    __shared__ int ts[256];
    const int t = threadIdx.x;

    int pv = 0;
    for (int i = t; i < (int)blockIdx.x; i += 256) pv += bsum[i];
    red[t] = pv; __syncthreads();
    for (int off = 128; off >= 1; off >>= 1) {
        if (t < off) red[t] += red[t + off];
        __syncthreads();
    }
    const int bpref = red[0];

    const int i0 = blockIdx.x * 1024 + t * 4;
    int v[4]; int s = 0;
    #pragma unroll
    for (int k = 0; k < 4; k++) {
        const int i = i0 + k;
        v[k] = (i < M_CNT) ? cnt[i] : 0;
        s += v[k];
    }
    ts[t] = s; __syncthreads();
    for (int off = 1; off < 256; off <<= 1) {
        const int x = (t >= off) ? ts[t - off] : 0;
        __syncthreads();
        ts[t] += x;
        __syncthreads();
    }
    int excl = ts[t] - s + bpref;
    #pragma unroll
    for (int k = 0; k < 4; k++) {
        const int i = i0 + k;
        if (i < M_CNT) cnt[i] = excl;
        excl += v[k];
    }
}

// ---------------------------------------------------------------------------
// K4: binned scatter (LDS cursors only). pair = {(rlocal<<17)|col, eexp}
// ---------------------------------------------------------------------------
__global__ __launch_bounds__(1024) void k_scatter(
    const int* __restrict__ ei,
    const float* __restrict__ f1,
    const float* __restrict__ f2,
    const int* __restrict__ cnt,
    uint2* __restrict__ pairs)
{
    __shared__ int cur[NB];
    const int c = blockIdx.x;
    for (int b = threadIdx.x; b < NB; b += 1024)
        cur[b] = cnt[b * C_CHUNKS + c];
    __syncthreads();

    const int e0 = c * CHUNK;
    for (int i = threadIdx.x; i < CHUNK; i += 1024) {
        const int r  = ei[e0 + i];
        const int cl = ei[N_EDGES + e0 + i];
        float x = f1[r] + f2[cl];
        x = (x >= 0.f) ? x : 0.2f * x;
        const float ee = __expf(x);
        const int pos = atomicAdd(&cur[r >> 6], 1);
        pairs[pos] = make_uint2(((unsigned)(r & 63) << 17) | (unsigned)cl,
                                __float_as_uint(ee));
    }
}

// ---------------------------------------------------------------------------
// K5: per-bucket streaming row-sort: pairs -> pairs2 (row-grouped) + rowptr.
// ROUND-6 TWEAK: stage the bucket's pairs in LDS during the count pass so
// the placement pass re-reads LDS, not global (cap 2048 w/ global fallback).
// ---------------------------------------------------------------------------
__global__ __launch_bounds__(256) void k_sort(
    const int* __restrict__ cnt,
    const uint2* __restrict__ pairs,
    uint2* __restrict__ pairs2,
    int* __restrict__ rowptr)
{
    __shared__ uint2 sp[SORT_LDS_CAP];
    __shared__ int cnt64[64];
    __shared__ int cur64[64];

    const int b   = blockIdx.x;
    const int tid = threadIdx.x;
    const int start = cnt[b * C_CHUNKS];
    const int end   = (b == NB - 1) ? N_EDGES : cnt[(b + 1) * C_CHUNKS];
    const int len   = end - start;

    if (tid < 64) cnt64[tid] = 0;
    __syncthreads();

    for (int i = tid; i < len; i += 256) {
        const uint2 p = pairs[start + i];
        if (i < SORT_LDS_CAP) sp[i] = p;
        atomicAdd(&cnt64[p.x >> 17], 1);
    }
    __syncthreads();

    if (tid < 64) {
        const int v = cnt64[tid];
        int s = v;
        #pragma unroll
        for (int off = 1; off < 64; off <<= 1) {
            const int x = __shfl_up(s, off, 64);
            if (tid >= off) s += x;
        }
        cur64[tid] = s - v;
        const int g = b * 64 + tid;
        if (g < N_NODES) rowptr[g] = start + s - v;
    }
    __syncthreads();

    for (int i = tid; i < len; i += 256) {
        const uint2 p = (i < SORT_LDS_CAP) ? sp[i] : pairs[start + i];
        const int pos = atomicAdd(&cur64[p.x >> 17], 1);
        pairs2[start + pos] = p;
    }
    if (b == 0 && tid == 0) rowptr[N_NODES] = N_EDGES;
}

// ---------------------------------------------------------------------------
// K6: wave-per-node aggregation. ROUND-6 REWRITE: 2 features per lane,
// 2 edges per wave-load (half-wave h=lane>>5 owns edge j+h; lane covers
// features 2(lane&31), 2(lane&31)+1). Halves load+VALU instructions per
// edge vs the 57.6us round-2 version; recombine halves via shfl_xor(32).
// ---------------------------------------------------------------------------
__global__ __launch_bounds__(256) void k_agg(
    const int* __restrict__ rowptr,
    const uint2* __restrict__ pairs2,
    const unsigned short* __restrict__ Whb,
    float* __restrict__ out)
{
    const int wid  = (blockIdx.x * 256 + threadIdx.x) >> 6;
    const int lane = threadIdx.x & 63;
    if (wid >= N_NODES) return;

    const int start = rowptr[wid];
    const int end   = rowptr[wid + 1];

    const int half = lane >> 5;          // which edge of the pair
    const int fl   = (lane & 31) << 1;   // feature base (0,2,...,62)

    float acc0 = 0.f, acc1 = 0.f, s = 0.f;
    int j = start;

    for (; j + 8 <= end; j += 8) {       // 8 edges = 4 pair-steps
        uint2 p[4];
        #pragma unroll
        for (int k = 0; k < 4; k++) p[k] = pairs2[j + 2 * k + half];
        unsigned w[4];
        #pragma unroll
        for (int k = 0; k < 4; k++)
            w[k] = *(const unsigned*)&Whb[(((int)(p[k].x & 0x1FFFFu)) << 6) + fl];
        #pragma unroll
        for (int k = 0; k < 4; k++) {
            const float ee = __uint_as_float(p[k].y);
            acc0 += ee * __uint_as_float(w[k] << 16);
            acc1 += ee * __uint_as_float(w[k] & 0xFFFF0000u);
            s    += ee;
        }
    }
    for (; j + 2 <= end; j += 2) {       // 2 edges
        const uint2 p = pairs2[j + half];
        const unsigned w = *(const unsigned*)&Whb[(((int)(p.x & 0x1FFFFu)) << 6) + fl];
        const float ee = __uint_as_float(p.y);
        acc0 += ee * __uint_as_float(w << 16);
        acc1 += ee * __uint_as_float(w & 0xFFFF0000u);
        s    += ee;
    }
    if (j < end && half == 0) {          // tail edge: half 0 only
        const uint2 p = pairs2[j];
        const unsigned w = *(const unsigned*)&Whb[(((int)(p.x & 0x1FFFFu)) << 6) + fl];
        const float ee = __uint_as_float(p.y);
        acc0 += ee * __uint_as_float(w << 16);
        acc1 += ee * __uint_as_float(w & 0xFFFF0000u);
        s    += ee;
    }

    // combine the two half-wave partial sums
    acc0 += __shfl_xor(acc0, 32, 64);
    acc1 += __shfl_xor(acc1, 32, 64);
    s    += __shfl_xor(s, 32, 64);

    if (half == 0) {
        const float inv = 1.f / (s + 1e-10f);
        float r0 = acc0 * inv;
        float r1 = acc1 * inv;
        r0 = (r0 > 0.f) ? r0 : expm1f(r0);
        r1 = (r1 > 0.f) ? r1 : expm1f(r1);
        *(float2*)&out[wid * OUT_F + fl] = make_float2(r0, r1);
    }
}

extern "C" void kernel_launch(void* const* d_in, const int* in_sizes, int n_in,
                              void* d_out, int out_size, void* d_ws, size_t ws_size,
                              hipStream_t stream) {
    const float* h  = (const float*)d_in[0];
    const float* W  = (const float*)d_in[1];
    const float* a1 = (const float*)d_in[2];
    const float* a2 = (const float*)d_in[3];
    const int* ei   = (const int*)d_in[4];
    float* out      = (float*)d_out;

    float* ws = (float*)d_ws;
    unsigned short* Whb = (unsigned short*)ws;        // 6.4M ushort = 3.2M f
    float* f1     = ws + 3200000;                     // 100,000
    float* f2     = f1 + N_NODES;                     // 100,000
    float* wa1    = f2 + N_NODES;                     // 128
    float* wa2    = wa1 + 128;                        // 128
    int*   cnt    = (int*)(wa2 + 128);                // 390,750
    int*   bsum   = cnt + M_CNT;                      // 384
    int*   rowptr = bsum + 384;                       // 100,002
    int*   pad    = rowptr + 100002;
    if ((size_t)(pad - (int*)ws) & 1) pad++;          // 8B align
    uint2* pairs  = (uint2*)pad;                      // 1.6M x 8B
    uint2* pairs2 = pairs + N_EDGES;                  // 1.6M x 8B

    k_hist   <<<C_CHUNKS + 1, 1024, 0, stream>>>(ei, cnt, W, a1, a2, wa1, wa2);
    k_scanA  <<<SCANA_BLOCKS, 256, 0, stream>>>(cnt, bsum);
    k_scanC  <<<SCANA_BLOCKS, 256, 0, stream>>>(cnt, bsum);
    k_gemm   <<<1250, 256, 0, stream>>>(h, W, wa1, wa2, Whb, f1, f2);
    k_scatter<<<C_CHUNKS, 1024, 0, stream>>>(ei, f1, f2, cnt, pairs);
    k_sort   <<<NB, 256, 0, stream>>>(cnt, pairs, pairs2, rowptr);
    k_agg    <<<(N_NODES * 64 + 255) / 256, 256, 0, stream>>>(rowptr, pairs2, Whb, out);
}